// Round 20
// baseline (1181.227 us; speedup 1.0000x reference)
//
#include <hip/hip_runtime.h>
#include <hip/hip_bf16.h>

#define BB 32
#define TT 120
#define EE 300
#define HH 256
#define VV 32000
#define CC 512
#define GG 49      // 7*7
#define KIN 556    // E+H
#define CF 25088   // C*49

typedef __attribute__((ext_vector_type(8))) short bf16x8;
typedef __attribute__((ext_vector_type(4))) float f32x4;

// ---- packed-bf16 helpers ----
__device__ __forceinline__ float bpair_lo(unsigned int u) { return __uint_as_float(u << 16); }
__device__ __forceinline__ float bpair_hi(unsigned int u) { return __uint_as_float(u & 0xFFFF0000u); }

__device__ __forceinline__ unsigned int packbf(float a, float b) {
    union { __hip_bfloat16 h; unsigned short u; } ua, ub;
    ua.h = __float2bfloat16(a); ub.h = __float2bfloat16(b);
    return (unsigned int)ua.u | ((unsigned int)ub.u << 16);
}

#if defined(__has_builtin)
#  if __has_builtin(__builtin_amdgcn_fdot2_f32_bf16)
#    define USE_DOT2 1
#  endif
#endif
#ifndef USE_DOT2
#  define USE_DOT2 0
#endif

#if USE_DOT2
typedef __bf16 bf2_t __attribute__((ext_vector_type(2)));
__device__ __forceinline__ float dot2bf(unsigned int w, unsigned int h, float c) {
    return __builtin_amdgcn_fdot2_f32_bf16(__builtin_bit_cast(bf2_t, w),
                                           __builtin_bit_cast(bf2_t, h), c, false);
}
#else
__device__ __forceinline__ float dot2bf(unsigned int w, unsigned int h, float c) {
    c = fmaf(bpair_lo(w), bpair_lo(h), c);
    c = fmaf(bpair_hi(w), bpair_hi(h), c);
    return c;
}
#endif

// ---------------- k_pre: fc2a(0..255) + gi_emb(256..975) + cvthh(976..1359) + h0(1360..1615) ----------------
__global__ void __launch_bounds__(256) k_pre(const float* __restrict__ features,
                                             const float* __restrict__ W_fc2,
                                             float* __restrict__ part,
                                             const float* __restrict__ W_hh,
                                             unsigned int* __restrict__ whh_bf,
                                             const float* __restrict__ W_init,
                                             const float* __restrict__ b_init,
                                             float* __restrict__ h0,
                                             const float* __restrict__ emb,
                                             const float* __restrict__ W_ih,
                                             float* __restrict__ gi) {
    __shared__ __align__(16) char smem[2 * 64 * 68 * 4];   // 34.8 KB union
    int bid = blockIdx.x;
    int tid = threadIdx.x;
    if (bid < 256) {
        // ---- fc2a ----
        float (*xs)[BB] = (float(*)[BB])smem;   // [98][32]
        int kc = bid;
        for (int idx = tid; idx < 98 * BB; idx += 256) {
            int ii = idx >> 5, b = idx & 31;
            int ig = kc * 98 + ii;
            int c = ig & 511, p = ig >> 9;
            xs[ii][b] = features[(size_t)b * CF + c * GG + p];
        }
        __syncthreads();
        int h = tid;
        float acc[BB];
#pragma unroll
        for (int b = 0; b < BB; ++b) acc[b] = 0.f;
        const float* wp = W_fc2 + (size_t)h * CF + kc * 98;
        for (int ii = 0; ii < 98; ii += 2) {
            float2 w2 = *(const float2*)(wp + ii);
            const float4* x0 = (const float4*)&xs[ii][0];
            const float4* x1 = (const float4*)&xs[ii + 1][0];
#pragma unroll
            for (int q = 0; q < 8; ++q) {
                float4 a4 = x0[q], b4 = x1[q];
                acc[4 * q + 0] += w2.x * a4.x + w2.y * b4.x;
                acc[4 * q + 1] += w2.x * a4.y + w2.y * b4.y;
                acc[4 * q + 2] += w2.x * a4.z + w2.y * b4.z;
                acc[4 * q + 3] += w2.x * a4.w + w2.y * b4.w;
            }
        }
        float* pp = part + (size_t)kc * (BB * 256) + h;
#pragma unroll
        for (int b = 0; b < BB; ++b) pp[b * 256] = acc[b];
    } else if (bid < 976) {
        // ---- gi_emb: partial GEMM over K=[0,300) ----
        float (*As)[68] = (float(*)[68])smem;
        float (*Bs)[68] = (float(*)[68])(smem + 17408);
        int idx = bid - 256;
        int n0 = (idx % 12) * 64;
        int m0 = (idx / 12) * 64;
        int tm = (tid & 15) * 4;
        int tn = (tid >> 4) * 4;
        float acc[4][4] = {};
        int mrA[4], klA[4];
#pragma unroll
        for (int s = 0; s < 4; ++s) {
            int slot = tid * 4 + s;
            mrA[s] = slot >> 4;
            klA[s] = (slot & 15) * 4;
        }
        float4 ra[4], rb[4];
#pragma unroll 1
        for (int kc = 0; kc < 5; ++kc) {
            int k0 = kc * 64;
#pragma unroll
            for (int s = 0; s < 4; ++s) {
                int m = m0 + mrA[s];
                int t = m >> 5, b = m & 31;
                int kg = k0 + klA[s];
                if (kg + 4 <= EE) {
                    ra[s] = *(const float4*)(emb + ((size_t)b * TT + t) * EE + kg);
                } else {
                    float tmp[4];
#pragma unroll
                    for (int q = 0; q < 4; ++q) {
                        int kq = kg + q;
                        tmp[q] = (kq < EE) ? emb[((size_t)b * TT + t) * EE + kq] : 0.f;
                    }
                    ra[s] = *(float4*)tmp;
                }
                int gidx = n0 + mrA[s];
                if (kg + 4 <= EE) {
                    rb[s] = *(const float4*)(W_ih + (size_t)gidx * KIN + kg);
                } else {
                    float tmp[4];
#pragma unroll
                    for (int q = 0; q < 4; ++q) {
                        int kq = kg + q;
                        tmp[q] = (kq < EE) ? W_ih[(size_t)gidx * KIN + kq] : 0.f;
                    }
                    rb[s] = *(float4*)tmp;
                }
            }
            __syncthreads();
#pragma unroll
            for (int s = 0; s < 4; ++s) {
                As[klA[s] + 0][mrA[s]] = ra[s].x;
                As[klA[s] + 1][mrA[s]] = ra[s].y;
                As[klA[s] + 2][mrA[s]] = ra[s].z;
                As[klA[s] + 3][mrA[s]] = ra[s].w;
                Bs[klA[s] + 0][mrA[s]] = rb[s].x;
                Bs[klA[s] + 1][mrA[s]] = rb[s].y;
                Bs[klA[s] + 2][mrA[s]] = rb[s].z;
                Bs[klA[s] + 3][mrA[s]] = rb[s].w;
            }
            __syncthreads();
            int kmax = (kc == 4) ? 44 : 64;    // 4*64+44 = 300
            for (int k = 0; k < kmax; ++k) {
                float4 av = *(const float4*)&As[k][tm];
                float4 bv = *(const float4*)&Bs[k][tn];
                const float* ap = (const float*)&av;
                const float* bp = (const float*)&bv;
#pragma unroll
                for (int i = 0; i < 4; ++i)
#pragma unroll
                    for (int j = 0; j < 4; ++j)
                        acc[i][j] = fmaf(ap[i], bp[j], acc[i][j]);
            }
        }
#pragma unroll
        for (int i = 0; i < 4; ++i) {
            int m = m0 + tm + i;
            float4 o;
            o.x = acc[i][0]; o.y = acc[i][1]; o.z = acc[i][2]; o.w = acc[i][3];
            *(float4*)(gi + (size_t)m * 768 + n0 + tn) = o;
        }
    } else if (bid < 1360) {
        // ---- cvthh ----
        int idx = (bid - 976) * 256 + tid;
        float2 w2 = *(const float2*)(W_hh + (size_t)idx * 2);
        whh_bf[idx] = packbf(w2.x, w2.y);
    } else {
        // ---- h0: fused mean + GEMM ----
        float* mf = (float*)smem;
        float (*red)[33] = (float(*)[33])(smem + 2048);
        int lb = bid - 1360;
        int b  = lb >> 3;
        int hc = lb & 7;
        {
            const float* p = features + (size_t)b * CF + (size_t)tid * 2 * GG;
            float s0 = 0.f, s1 = 0.f;
#pragma unroll
            for (int i = 0; i < GG; ++i) s0 += p[i];
#pragma unroll
            for (int i = 0; i < GG; ++i) s1 += p[GG + i];
            mf[tid * 2]     = s0 * (1.0f / 49.0f);
            mf[tid * 2 + 1] = s1 * (1.0f / 49.0f);
        }
        __syncthreads();
        int h  = tid & 31;
        int kg = tid >> 5;
        int gh = hc * 32 + h;
        const float* w = W_init + (size_t)gh * CC + kg * 64;
        const float* m = mf + kg * 64;
        float s = 0.f;
#pragma unroll
        for (int k = 0; k < 64; k += 4) {
            float4 w4 = *(const float4*)(w + k);
            s += m[k] * w4.x + m[k + 1] * w4.y + m[k + 2] * w4.z + m[k + 3] * w4.w;
        }
        red[kg][h] = s;
        __syncthreads();
        if (tid < 32) {
            float t = b_init[hc * 32 + tid];
#pragma unroll
            for (int g = 0; g < 8; ++g) t += red[g][tid];
            h0[b * HH + hc * 32 + tid] = t;
        }
    }
}

// ---------------- fc2 stage B: parallel reduce, grid (32 b, 8 hc) ----------------
__global__ void __launch_bounds__(256) k_fc2b(const float* __restrict__ part,
                                              const float* __restrict__ b_fc2,
                                              float* __restrict__ feat) {
    int b  = blockIdx.x;
    int hc = blockIdx.y;
    int h  = threadIdx.x & 31;
    int kg = threadIdx.x >> 5;
    int gh = hc * 32 + h;
    __shared__ float red[8][33];
    const float* pp = part + (size_t)kg * 32 * (BB * 256) + b * 256 + gh;
    float s = 0.f;
#pragma unroll
    for (int kc = 0; kc < 32; ++kc) s += pp[(size_t)kc * (BB * 256)];
    red[kg][h] = s;
    __syncthreads();
    if (threadIdx.x < 32) {
        float t = b_fc2[hc * 32 + threadIdx.x];
#pragma unroll
        for (int g = 0; g < 8; ++g) t += red[g][threadIdx.x];
        feat[b * HH + hc * 32 + threadIdx.x] = t;
    }
}

// ---------------- GRU body: W rows 0..255 cached in LDS ([kk4][jp] uint4, +1 pad) ----------------
__device__ __forceinline__ void gru_body(int b, const float* __restrict__ h0,
                                         const float* __restrict__ gi,
                                         const unsigned int* __restrict__ whh_bf,
                                         const float* __restrict__ b_hh,
                                         const float* __restrict__ feat,
                                         const float* __restrict__ W_ih,
                                         const float* __restrict__ b_ih,
                                         __hip_bfloat16* __restrict__ hA,
                                         unsigned int* h_pk, float* hf,
                                         float* r_sh, float* z_sh, float* ff,
                                         uint4* lds_w) {
    int jp = threadIdx.x;
    int j  = jp & 255;
    int g  = jp >> 8;
    const unsigned int* wr = whh_bf + (size_t)jp * 128;
    float bias = b_hh[jp];
    if (jp < HH) hf[jp] = h0[b * HH + jp];
    if (jp >= 512 && jp < 576) *(float4*)&ff[(jp - 512) * 4] = *(const float4*)(feat + b * HH + (jp - 512) * 4);
    // W-cache: rows 0..255 (8192 uint4), linear gather, padded-transposed store (conflict-free)
    {
        const uint4* whh4 = (const uint4*)whh_bf;
        for (int idx = jp; idx < 8192; idx += 768)
            lds_w[(idx & 31) * 257 + (idx >> 5)] = whh4[idx];
    }
    __syncthreads();
    if (jp < 128) h_pk[jp] = packbf(hf[2 * jp], hf[2 * jp + 1]);
    __syncthreads();

    // gf = feat[b] @ W_ih[jp, 300:556] + b_ih[jp]
    float ga = 0.f;
    const float* wih = W_ih + (size_t)jp * KIN + EE;
#pragma unroll 8
    for (int k = 0; k < HH; k += 4) {
        float4 w4 = *(const float4*)(wih + k);
        ga = fmaf(ff[k], w4.x, ga);
        ga = fmaf(ff[k + 1], w4.y, ga);
        ga = fmaf(ff[k + 2], w4.z, ga);
        ga = fmaf(ff[k + 3], w4.w, ga);
    }
    float gf = ga + b_ih[jp];

    const uint4* wl = lds_w + jp;   // valid when jp < 256

    for (int t = 0; t < TT; ++t) {
        float a0 = 0.f, a1 = 0.f, a2 = 0.f, a3 = 0.f;
        if (jp < 256) {
#pragma unroll
            for (int kk = 0; kk < 128; kk += 4) {
                uint4 wq = wl[(kk >> 2) * 257];
                uint4 hq = *(const uint4*)&h_pk[kk];
                a0 = dot2bf(wq.x, hq.x, a0);
                a1 = dot2bf(wq.y, hq.y, a1);
                a2 = dot2bf(wq.z, hq.z, a2);
                a3 = dot2bf(wq.w, hq.w, a3);
            }
        } else {
#pragma unroll
            for (int kk = 0; kk < 128; kk += 4) {
                uint4 wq = *(const uint4*)(wr + kk);
                uint4 hq = *(const uint4*)&h_pk[kk];
                a0 = dot2bf(wq.x, hq.x, a0);
                a1 = dot2bf(wq.y, hq.y, a1);
                a2 = dot2bf(wq.z, hq.z, a2);
                a3 = dot2bf(wq.w, hq.w, a3);
            }
        }
        float a = (a0 + a1) + (a2 + a3);
        float gx = gi[((size_t)t * BB + b) * 768 + jp] + gf;
        if (g == 0)      r_sh[j] = 1.f / (1.f + __expf(-(gx + a + bias)));
        else if (g == 1) z_sh[j] = 1.f / (1.f + __expf(-(gx + a + bias)));
        __syncthreads();
        if (g == 2) {
            float n  = tanhf(gx + r_sh[j] * (a + bias));
            float z  = z_sh[j];
            float hn = (1.f - z) * n + z * hf[j];
            hf[j] = hn;
            hA[((size_t)b * TT + t) * HH + j] = __float2bfloat16(hn);
        }
        __syncthreads();
        if (jp < 128) h_pk[jp] = packbf(hf[2 * jp], hf[2 * jp + 1]);
        __syncthreads();
    }
}

#define GRU_DYN_LDS (32 * 257 * 16)   // 131,584 B W-cache

// ---------------- standalone GRU (fallback path) ----------------
__global__ void __launch_bounds__(768, 1) k_gru(const float* __restrict__ h0,
                                                const float* __restrict__ gi,
                                                const unsigned int* __restrict__ whh_bf,
                                                const float* __restrict__ b_hh,
                                                const float* __restrict__ feat,
                                                const float* __restrict__ W_ih,
                                                const float* __restrict__ b_ih,
                                                __hip_bfloat16* __restrict__ hA) {
    __shared__ unsigned int h_pk[128];
    __shared__ float hf[256];
    __shared__ float r_sh[256];
    __shared__ float z_sh[256];
    __shared__ float ff[256];
    extern __shared__ __align__(16) char dynsm[];
    gru_body(blockIdx.x, h0, gi, whh_bf, b_hh, feat, W_ih, b_ih, hA, h_pk, hf, r_sh, z_sh, ff,
             (uint4*)dynsm);
}

// ---------------- fused GRU + W_fc cvt: blocks 0..31 gru, 32.. cvt (idle CUs) ----------------
#define CVT_N4 2048000   // 32000*256 floats = 2,048,000 float4
__global__ void __launch_bounds__(768, 1) k_gru_cvt(const float* __restrict__ h0,
                                                    const float* __restrict__ gi,
                                                    const unsigned int* __restrict__ whh_bf,
                                                    const float* __restrict__ b_hh,
                                                    const float* __restrict__ feat,
                                                    const float* __restrict__ W_ih,
                                                    const float* __restrict__ b_ih,
                                                    __hip_bfloat16* __restrict__ hA,
                                                    const float* __restrict__ W_fc,
                                                    __hip_bfloat16* __restrict__ wfc) {
    if (blockIdx.x >= 32) {
        size_t base = (size_t)(blockIdx.x - 32) * (768 * 4) + threadIdx.x;
#pragma unroll
        for (int q = 0; q < 4; ++q) {
            size_t fi = base + (size_t)q * 768;
            if (fi < CVT_N4) {
                float4 v = *((const float4*)W_fc + fi);
                __hip_bfloat16 o[4];
                o[0] = __float2bfloat16(v.x);
                o[1] = __float2bfloat16(v.y);
                o[2] = __float2bfloat16(v.z);
                o[3] = __float2bfloat16(v.w);
                *((uint2*)wfc + fi) = *(uint2*)o;
            }
        }
        return;
    }
    __shared__ unsigned int h_pk[128];
    __shared__ float hf[256];
    __shared__ float r_sh[256];
    __shared__ float z_sh[256];
    __shared__ float ff[256];
    extern __shared__ __align__(16) char dynsm[];
    gru_body(blockIdx.x, h0, gi, whh_bf, b_hh, feat, W_ih, b_ih, hA, h_pk, hf, r_sh, z_sh, ff,
             (uint4*)dynsm);
}

// ---------------- W_fc f32 -> bf16 (fallback path) ----------------
__global__ void k_cvt(const float* __restrict__ src, __hip_bfloat16* __restrict__ dst) {
    size_t i = ((size_t)blockIdx.x * 256 + threadIdx.x) * 4;
    float4 v = *(const float4*)(src + i);
    __hip_bfloat16 o[4];
    o[0] = __float2bfloat16(v.x);
    o[1] = __float2bfloat16(v.y);
    o[2] = __float2bfloat16(v.z);
    o[3] = __float2bfloat16(v.w);
    *(uint2*)(dst + i) = *(uint2*)o;
}

// ---------------- logits: 256x128 tile MFMA GEMM, grid (250 nt, 15 mt) ----------------
__global__ void __launch_bounds__(512) k_logits(const __hip_bfloat16* __restrict__ hA,
                                                const __hip_bfloat16* __restrict__ wfc,
                                                const float* __restrict__ b_fc,
                                                float* __restrict__ out) {
    __shared__ short As[256][64];   // 32 KB
    __shared__ short Bs[128][64];   // 16 KB
    char* AsB = (char*)As;
    char* BsB = (char*)Bs;

    int nt = blockIdx.x;   // 0..249
    int mt = blockIdx.y;   // 0..14
    int tid  = threadIdx.x;
    int wave = tid >> 6, lane = tid & 63;
    int wm = wave >> 1;
    int wn = wave & 1;
    int lr = lane & 15;
    int lk = lane >> 4;

    int rs = tid >> 3;
    int cs = tid & 7;
    const short* Ag = (const short*)hA  + ((size_t)mt * 256 + rs) * HH + cs * 8;
    const short* Bg = (const short*)wfc + ((size_t)nt * 128 + rs) * HH + cs * 8;
    int wofsA[4], wofsB[2];
#pragma unroll
    for (int s = 0; s < 4; ++s) {
        int row = s * 64 + rs;
        wofsA[s] = row * 128 + ((cs ^ (row & 7)) * 16);
    }
#pragma unroll
    for (int s = 0; s < 2; ++s) {
        int row = s * 64 + rs;
        wofsB[s] = row * 128 + ((cs ^ (row & 7)) * 16);
    }

    f32x4 acc[4][4] = {};

#define LOADT(kt, GA, GB)                                                        \
    do {                                                                         \
        _Pragma("unroll") for (int s = 0; s < 4; ++s)                            \
            GA[s] = *(const bf16x8*)(Ag + (size_t)s * 64 * HH + (kt) * 64);      \
        _Pragma("unroll") for (int s = 0; s < 2; ++s)                            \
            GB[s] = *(const bf16x8*)(Bg + (size_t)s * 64 * HH + (kt) * 64);      \
    } while (0)

#define STORET(GA, GB)                                                           \
    do {                                                                         \
        _Pragma("unroll") for (int s = 0; s < 4; ++s)                            \
            *(bf16x8*)(AsB + wofsA[s]) = GA[s];                                  \
        _Pragma("unroll") for (int s = 0; s < 2; ++s)                            \
            *(bf16x8*)(BsB + wofsB[s]) = GB[s];                                  \
    } while (0)

#define COMPUTE()                                                                \
    do {                                                                         \
        _Pragma("unroll") for (int kk = 0; kk < 2; ++kk) {                       \
            bf16x8 af[4], bg[4];                                                 \
            _Pragma("unroll") for (int i = 0; i < 4; ++i) {                      \
                int r = wm * 64 + i * 16 + lr;                                   \
                af[i] = *(const bf16x8*)(AsB + r * 128 + (((kk * 4 + lk) ^ (r & 7)) * 16)); \
            }                                                                    \
            _Pragma("unroll") for (int j = 0; j < 4; ++j) {                      \
                int r = wn * 64 + j * 16 + lr;                                   \
                bg[j] = *(const bf16x8*)(BsB + r * 128 + (((kk * 4 + lk) ^ (r & 7)) * 16)); \
            }                                                                    \
            _Pragma("unroll") for (int i = 0; i < 4; ++i)                        \
                _Pragma("unroll") for (int j = 0; j < 4; ++j)                    \
                    acc[i][j] = __builtin_amdgcn_mfma_f32_16x16x32_bf16(af[i], bg[j], acc[i][j], 0, 0, 0); \
        }                                                                        \
    } while (0)

    bf16x8 gA[4], gB[2], gA2[4], gB2[2];
    LOADT(0, gA, gB);
    STORET(gA, gB);   LOADT(1, gA2, gB2); __syncthreads(); COMPUTE(); __syncthreads();
    STORET(gA2, gB2); LOADT(2, gA, gB);   __syncthreads(); COMPUTE(); __syncthreads();
    STORET(gA, gB);   LOADT(3, gA2, gB2); __syncthreads(); COMPUTE(); __syncthreads();
    STORET(gA2, gB2);                     __syncthreads(); COMPUTE();

#undef LOADT
#undef STORET
#undef COMPUTE

    int m_base = mt * 256 + wm * 64;
    int n_base = nt * 128 + wn * 64;
#pragma unroll
    for (int i = 0; i < 4; ++i) {
#pragma unroll
        for (int j = 0; j < 4; ++j) {
            int v = n_base + j * 16 + lr;
            float bias = b_fc[v];
#pragma unroll
            for (int q = 0; q < 4; ++q) {
                int m = m_base + i * 16 + lk * 4 + q;
                out[(size_t)m * VV + v] = acc[i][j][q] + bias;
            }
        }
    }
}

extern "C" void kernel_launch(void* const* d_in, const int* in_sizes, int n_in,
                              void* d_out, int out_size, void* d_ws, size_t ws_size,
                              hipStream_t stream) {
    (void)in_sizes; (void)n_in; (void)out_size;
    const float* features   = (const float*)d_in[0];
    const float* embeddings = (const float*)d_in[1];
    const float* W_init     = (const float*)d_in[2];
    const float* b_init     = (const float*)d_in[3];
    const float* W_fc2      = (const float*)d_in[4];
    const float* b_fc2      = (const float*)d_in[5];
    const float* W_ih       = (const float*)d_in[6];
    const float* b_ih       = (const float*)d_in[7];
    const float* W_hh       = (const float*)d_in[8];
    const float* b_hh       = (const float*)d_in[9];
    const float* W_fc       = (const float*)d_in[10];
    const float* b_fc       = (const float*)d_in[11];

    char* ws = (char*)d_ws;
    float* feat   = (float*)(ws + 65536);                      // 32 KB
    float* hbuf0  = (float*)(ws + 98304);                      // 32 KB
    __hip_bfloat16* hA = (__hip_bfloat16*)(ws + 131072);       // 1.875 MB (ends 2,097,152)
    float* gi     = (float*)(ws + 2097152);                    // 11.25 MB (ends 13,893,632)
    unsigned int* whh_bf = (unsigned int*)(ws + 13893632);     // 393 KB (ends 14,286,848)
    float* outp = (float*)d_out;
    // part (8 MB) lives in d_out's tail: consumed by fc2b, fully overwritten by k_logits later
    float* part = (float*)d_out + 120782848;                   // 122,880,000 - 2,097,152

    // disjoint-wfc layout needs 14,286,848 + 16,384,000 = 30,670,848 bytes
    int fused = (ws_size >= 30670848u);
    __hip_bfloat16* wfc = fused ? (__hip_bfloat16*)(ws + 14286848)   // disjoint from gi
                                : (__hip_bfloat16*)(ws + 2097152);   // overlays gi (after gru)

    k_pre<<<1616, 256, 0, stream>>>(features, W_fc2, part, W_hh, whh_bf, W_init, b_init,
                                    hbuf0, embeddings, W_ih, gi);
    k_fc2b<<<dim3(32, 8), 256, 0, stream>>>(part, b_fc2, feat);
    if (fused) {
        k_gru_cvt<<<32 + 667, 768, GRU_DYN_LDS, stream>>>(hbuf0, gi, whh_bf, b_hh, feat,
                                                          W_ih, b_ih, hA, W_fc, wfc);
    } else {
        k_gru<<<32, 768, GRU_DYN_LDS, stream>>>(hbuf0, gi, whh_bf, b_hh, feat, W_ih, b_ih, hA);
        k_cvt<<<8000, 256, 0, stream>>>(W_fc, wfc);
    }
    k_logits<<<dim3(250, 15), 512, 0, stream>>>(hA, wfc, b_fc, outp);
}

// Round 21
// 389.651 us; speedup vs baseline: 3.0315x; 3.0315x over previous
//
#include <hip/hip_runtime.h>
#include <hip/hip_bf16.h>

#define BB 32
#define TT 120
#define EE 300
#define HH 256
#define VV 32000
#define CC 512
#define GG 49      // 7*7
#define KIN 556    // E+H
#define CF 25088   // C*49

typedef __attribute__((ext_vector_type(8))) short bf16x8;
typedef __attribute__((ext_vector_type(4))) float f32x4;

// ---- packed-bf16 helpers ----
__device__ __forceinline__ float bpair_lo(unsigned int u) { return __uint_as_float(u << 16); }
__device__ __forceinline__ float bpair_hi(unsigned int u) { return __uint_as_float(u & 0xFFFF0000u); }

__device__ __forceinline__ unsigned int packbf(float a, float b) {
    union { __hip_bfloat16 h; unsigned short u; } ua, ub;
    ua.h = __float2bfloat16(a); ub.h = __float2bfloat16(b);
    return (unsigned int)ua.u | ((unsigned int)ub.u << 16);
}

#if defined(__has_builtin)
#  if __has_builtin(__builtin_amdgcn_fdot2_f32_bf16)
#    define USE_DOT2 1
#  endif
#endif
#ifndef USE_DOT2
#  define USE_DOT2 0
#endif

#if USE_DOT2
typedef __bf16 bf2_t __attribute__((ext_vector_type(2)));
__device__ __forceinline__ float dot2bf(unsigned int w, unsigned int h, float c) {
    return __builtin_amdgcn_fdot2_f32_bf16(__builtin_bit_cast(bf2_t, w),
                                           __builtin_bit_cast(bf2_t, h), c, false);
}
#else
__device__ __forceinline__ float dot2bf(unsigned int w, unsigned int h, float c) {
    c = fmaf(bpair_lo(w), bpair_lo(h), c);
    c = fmaf(bpair_hi(w), bpair_hi(h), c);
    return c;
}
#endif

// ---------------- k_pre: fc2a(0..255) + gi_emb(256..975) + cvthh(976..1359) + h0(1360..1615) ----------------
__global__ void __launch_bounds__(256) k_pre(const float* __restrict__ features,
                                             const float* __restrict__ W_fc2,
                                             float* __restrict__ part,
                                             const float* __restrict__ W_hh,
                                             unsigned int* __restrict__ whh_bf,
                                             const float* __restrict__ W_init,
                                             const float* __restrict__ b_init,
                                             float* __restrict__ h0,
                                             const float* __restrict__ emb,
                                             const float* __restrict__ W_ih,
                                             float* __restrict__ gi) {
    __shared__ __align__(16) char smem[2 * 64 * 68 * 4];   // 34.8 KB union
    int bid = blockIdx.x;
    int tid = threadIdx.x;
    if (bid < 256) {
        // ---- fc2a ----
        float (*xs)[BB] = (float(*)[BB])smem;   // [98][32]
        int kc = bid;
        for (int idx = tid; idx < 98 * BB; idx += 256) {
            int ii = idx >> 5, b = idx & 31;
            int ig = kc * 98 + ii;
            int c = ig & 511, p = ig >> 9;
            xs[ii][b] = features[(size_t)b * CF + c * GG + p];
        }
        __syncthreads();
        int h = tid;
        float acc[BB];
#pragma unroll
        for (int b = 0; b < BB; ++b) acc[b] = 0.f;
        const float* wp = W_fc2 + (size_t)h * CF + kc * 98;
        for (int ii = 0; ii < 98; ii += 2) {
            float2 w2 = *(const float2*)(wp + ii);
            const float4* x0 = (const float4*)&xs[ii][0];
            const float4* x1 = (const float4*)&xs[ii + 1][0];
#pragma unroll
            for (int q = 0; q < 8; ++q) {
                float4 a4 = x0[q], b4 = x1[q];
                acc[4 * q + 0] += w2.x * a4.x + w2.y * b4.x;
                acc[4 * q + 1] += w2.x * a4.y + w2.y * b4.y;
                acc[4 * q + 2] += w2.x * a4.z + w2.y * b4.z;
                acc[4 * q + 3] += w2.x * a4.w + w2.y * b4.w;
            }
        }
        float* pp = part + (size_t)kc * (BB * 256) + h;
#pragma unroll
        for (int b = 0; b < BB; ++b) pp[b * 256] = acc[b];
    } else if (bid < 976) {
        // ---- gi_emb: partial GEMM over K=[0,300) ----
        float (*As)[68] = (float(*)[68])smem;
        float (*Bs)[68] = (float(*)[68])(smem + 17408);
        int idx = bid - 256;
        int n0 = (idx % 12) * 64;
        int m0 = (idx / 12) * 64;
        int tm = (tid & 15) * 4;
        int tn = (tid >> 4) * 4;
        float acc[4][4] = {};
        int mrA[4], klA[4];
#pragma unroll
        for (int s = 0; s < 4; ++s) {
            int slot = tid * 4 + s;
            mrA[s] = slot >> 4;
            klA[s] = (slot & 15) * 4;
        }
        float4 ra[4], rb[4];
#pragma unroll 1
        for (int kc = 0; kc < 5; ++kc) {
            int k0 = kc * 64;
#pragma unroll
            for (int s = 0; s < 4; ++s) {
                int m = m0 + mrA[s];
                int t = m >> 5, b = m & 31;
                int kg = k0 + klA[s];
                if (kg + 4 <= EE) {
                    ra[s] = *(const float4*)(emb + ((size_t)b * TT + t) * EE + kg);
                } else {
                    float tmp[4];
#pragma unroll
                    for (int q = 0; q < 4; ++q) {
                        int kq = kg + q;
                        tmp[q] = (kq < EE) ? emb[((size_t)b * TT + t) * EE + kq] : 0.f;
                    }
                    ra[s] = *(float4*)tmp;
                }
                int gidx = n0 + mrA[s];
                if (kg + 4 <= EE) {
                    rb[s] = *(const float4*)(W_ih + (size_t)gidx * KIN + kg);
                } else {
                    float tmp[4];
#pragma unroll
                    for (int q = 0; q < 4; ++q) {
                        int kq = kg + q;
                        tmp[q] = (kq < EE) ? W_ih[(size_t)gidx * KIN + kq] : 0.f;
                    }
                    rb[s] = *(float4*)tmp;
                }
            }
            __syncthreads();
#pragma unroll
            for (int s = 0; s < 4; ++s) {
                As[klA[s] + 0][mrA[s]] = ra[s].x;
                As[klA[s] + 1][mrA[s]] = ra[s].y;
                As[klA[s] + 2][mrA[s]] = ra[s].z;
                As[klA[s] + 3][mrA[s]] = ra[s].w;
                Bs[klA[s] + 0][mrA[s]] = rb[s].x;
                Bs[klA[s] + 1][mrA[s]] = rb[s].y;
                Bs[klA[s] + 2][mrA[s]] = rb[s].z;
                Bs[klA[s] + 3][mrA[s]] = rb[s].w;
            }
            __syncthreads();
            int kmax = (kc == 4) ? 44 : 64;    // 4*64+44 = 300
            for (int k = 0; k < kmax; ++k) {
                float4 av = *(const float4*)&As[k][tm];
                float4 bv = *(const float4*)&Bs[k][tn];
                const float* ap = (const float*)&av;
                const float* bp = (const float*)&bv;
#pragma unroll
                for (int i = 0; i < 4; ++i)
#pragma unroll
                    for (int j = 0; j < 4; ++j)
                        acc[i][j] = fmaf(ap[i], bp[j], acc[i][j]);
            }
        }
#pragma unroll
        for (int i = 0; i < 4; ++i) {
            int m = m0 + tm + i;
            float4 o;
            o.x = acc[i][0]; o.y = acc[i][1]; o.z = acc[i][2]; o.w = acc[i][3];
            *(float4*)(gi + (size_t)m * 768 + n0 + tn) = o;
        }
    } else if (bid < 1360) {
        // ---- cvthh ----
        int idx = (bid - 976) * 256 + tid;
        float2 w2 = *(const float2*)(W_hh + (size_t)idx * 2);
        whh_bf[idx] = packbf(w2.x, w2.y);
    } else {
        // ---- h0: fused mean + GEMM ----
        float* mf = (float*)smem;
        float (*red)[33] = (float(*)[33])(smem + 2048);
        int lb = bid - 1360;
        int b  = lb >> 3;
        int hc = lb & 7;
        {
            const float* p = features + (size_t)b * CF + (size_t)tid * 2 * GG;
            float s0 = 0.f, s1 = 0.f;
#pragma unroll
            for (int i = 0; i < GG; ++i) s0 += p[i];
#pragma unroll
            for (int i = 0; i < GG; ++i) s1 += p[GG + i];
            mf[tid * 2]     = s0 * (1.0f / 49.0f);
            mf[tid * 2 + 1] = s1 * (1.0f / 49.0f);
        }
        __syncthreads();
        int h  = tid & 31;
        int kg = tid >> 5;
        int gh = hc * 32 + h;
        const float* w = W_init + (size_t)gh * CC + kg * 64;
        const float* m = mf + kg * 64;
        float s = 0.f;
#pragma unroll
        for (int k = 0; k < 64; k += 4) {
            float4 w4 = *(const float4*)(w + k);
            s += m[k] * w4.x + m[k + 1] * w4.y + m[k + 2] * w4.z + m[k + 3] * w4.w;
        }
        red[kg][h] = s;
        __syncthreads();
        if (tid < 32) {
            float t = b_init[hc * 32 + tid];
#pragma unroll
            for (int g = 0; g < 8; ++g) t += red[g][tid];
            h0[b * HH + hc * 32 + tid] = t;
        }
    }
}

// ---------------- fc2 stage B: parallel reduce, grid (32 b, 8 hc) ----------------
__global__ void __launch_bounds__(256) k_fc2b(const float* __restrict__ part,
                                              const float* __restrict__ b_fc2,
                                              float* __restrict__ feat) {
    int b  = blockIdx.x;
    int hc = blockIdx.y;
    int h  = threadIdx.x & 31;
    int kg = threadIdx.x >> 5;
    int gh = hc * 32 + h;
    __shared__ float red[8][33];
    const float* pp = part + (size_t)kg * 32 * (BB * 256) + b * 256 + gh;
    float s = 0.f;
#pragma unroll
    for (int kc = 0; kc < 32; ++kc) s += pp[(size_t)kc * (BB * 256)];
    red[kg][h] = s;
    __syncthreads();
    if (threadIdx.x < 32) {
        float t = b_fc2[hc * 32 + threadIdx.x];
#pragma unroll
        for (int g = 0; g < 8; ++g) t += red[g][threadIdx.x];
        feat[b * HH + hc * 32 + threadIdx.x] = t;
    }
}

// ---------------- GRU body: prologue computes time-invariant feat-part gf, then scan ----------------
__device__ __forceinline__ void gru_body(int b, const float* __restrict__ h0,
                                         const float* __restrict__ gi,
                                         const unsigned int* __restrict__ whh_bf,
                                         const float* __restrict__ b_hh,
                                         const float* __restrict__ feat,
                                         const float* __restrict__ W_ih,
                                         const float* __restrict__ b_ih,
                                         __hip_bfloat16* __restrict__ hA,
                                         unsigned int* h_pk, float* hf,
                                         float* r_sh, float* z_sh, float* ff) {
    int jp = threadIdx.x;
    int j  = jp & 255;
    int g  = jp >> 8;
    const unsigned int* wr = whh_bf + (size_t)jp * 128;
    float bias = b_hh[jp];
    if (jp < HH) hf[jp] = h0[b * HH + jp];
    if (jp >= 512 && jp < 576) *(float4*)&ff[(jp - 512) * 4] = *(const float4*)(feat + b * HH + (jp - 512) * 4);
    __syncthreads();
    if (jp < 128) h_pk[jp] = packbf(hf[2 * jp], hf[2 * jp + 1]);
    __syncthreads();

    // gf = feat[b] @ W_ih[jp, 300:556] + b_ih[jp]
    float ga = 0.f;
    const float* wih = W_ih + (size_t)jp * KIN + EE;
#pragma unroll 8
    for (int k = 0; k < HH; k += 4) {
        float4 w4 = *(const float4*)(wih + k);
        ga = fmaf(ff[k], w4.x, ga);
        ga = fmaf(ff[k + 1], w4.y, ga);
        ga = fmaf(ff[k + 2], w4.z, ga);
        ga = fmaf(ff[k + 3], w4.w, ga);
    }
    float gf = ga + b_ih[jp];

    for (int t = 0; t < TT; ++t) {
        float a0 = 0.f, a1 = 0.f, a2 = 0.f, a3 = 0.f;
#pragma unroll
        for (int kk = 0; kk < 128; kk += 4) {
            uint4 wq = *(const uint4*)(wr + kk);
            uint4 hq = *(const uint4*)&h_pk[kk];
            a0 = dot2bf(wq.x, hq.x, a0);
            a1 = dot2bf(wq.y, hq.y, a1);
            a2 = dot2bf(wq.z, hq.z, a2);
            a3 = dot2bf(wq.w, hq.w, a3);
        }
        float a = (a0 + a1) + (a2 + a3);
        float gx = gi[((size_t)t * BB + b) * 768 + jp] + gf;
        if (g == 0)      r_sh[j] = 1.f / (1.f + __expf(-(gx + a + bias)));
        else if (g == 1) z_sh[j] = 1.f / (1.f + __expf(-(gx + a + bias)));
        __syncthreads();
        if (g == 2) {
            float n  = tanhf(gx + r_sh[j] * (a + bias));
            float z  = z_sh[j];
            float hn = (1.f - z) * n + z * hf[j];
            hf[j] = hn;
            hA[((size_t)b * TT + t) * HH + j] = __float2bfloat16(hn);
        }
        __syncthreads();
        if (jp < 128) h_pk[jp] = packbf(hf[2 * jp], hf[2 * jp + 1]);
        __syncthreads();
    }
}

// ---------------- standalone GRU (fallback path) ----------------
__global__ void __launch_bounds__(768, 3) k_gru(const float* __restrict__ h0,
                                                const float* __restrict__ gi,
                                                const unsigned int* __restrict__ whh_bf,
                                                const float* __restrict__ b_hh,
                                                const float* __restrict__ feat,
                                                const float* __restrict__ W_ih,
                                                const float* __restrict__ b_ih,
                                                __hip_bfloat16* __restrict__ hA) {
    __shared__ unsigned int h_pk[128];
    __shared__ float hf[256];
    __shared__ float r_sh[256];
    __shared__ float z_sh[256];
    __shared__ float ff[256];
    gru_body(blockIdx.x, h0, gi, whh_bf, b_hh, feat, W_ih, b_ih, hA, h_pk, hf, r_sh, z_sh, ff);
}

// ---------------- fused GRU + W_fc cvt: blocks 0..31 gru, 32.. cvt (idle CUs) ----------------
#define CVT_N4 2048000   // 32000*256 floats = 2,048,000 float4
__global__ void __launch_bounds__(768, 3) k_gru_cvt(const float* __restrict__ h0,
                                                    const float* __restrict__ gi,
                                                    const unsigned int* __restrict__ whh_bf,
                                                    const float* __restrict__ b_hh,
                                                    const float* __restrict__ feat,
                                                    const float* __restrict__ W_ih,
                                                    const float* __restrict__ b_ih,
                                                    __hip_bfloat16* __restrict__ hA,
                                                    const float* __restrict__ W_fc,
                                                    __hip_bfloat16* __restrict__ wfc) {
    if (blockIdx.x >= 32) {
        size_t base = (size_t)(blockIdx.x - 32) * (768 * 4) + threadIdx.x;
#pragma unroll
        for (int q = 0; q < 4; ++q) {
            size_t fi = base + (size_t)q * 768;
            if (fi < CVT_N4) {
                float4 v = *((const float4*)W_fc + fi);
                __hip_bfloat16 o[4];
                o[0] = __float2bfloat16(v.x);
                o[1] = __float2bfloat16(v.y);
                o[2] = __float2bfloat16(v.z);
                o[3] = __float2bfloat16(v.w);
                *((uint2*)wfc + fi) = *(uint2*)o;
            }
        }
        return;
    }
    __shared__ unsigned int h_pk[128];
    __shared__ float hf[256];
    __shared__ float r_sh[256];
    __shared__ float z_sh[256];
    __shared__ float ff[256];
    gru_body(blockIdx.x, h0, gi, whh_bf, b_hh, feat, W_ih, b_ih, hA, h_pk, hf, r_sh, z_sh, ff);
}

// ---------------- W_fc f32 -> bf16 (fallback path) ----------------
__global__ void k_cvt(const float* __restrict__ src, __hip_bfloat16* __restrict__ dst) {
    size_t i = ((size_t)blockIdx.x * 256 + threadIdx.x) * 4;
    float4 v = *(const float4*)(src + i);
    __hip_bfloat16 o[4];
    o[0] = __float2bfloat16(v.x);
    o[1] = __float2bfloat16(v.y);
    o[2] = __float2bfloat16(v.z);
    o[3] = __float2bfloat16(v.w);
    *(uint2*)(dst + i) = *(uint2*)o;
}

// ---------------- logits: 256x128 tile MFMA GEMM, grid (250 nt, 15 mt) ----------------
__global__ void __launch_bounds__(512) k_logits(const __hip_bfloat16* __restrict__ hA,
                                                const __hip_bfloat16* __restrict__ wfc,
                                                const float* __restrict__ b_fc,
                                                float* __restrict__ out) {
    __shared__ short As[256][64];   // 32 KB
    __shared__ short Bs[128][64];   // 16 KB
    char* AsB = (char*)As;
    char* BsB = (char*)Bs;

    int nt = blockIdx.x;   // 0..249 (fast-varying: nt%8 ~ XCD affinity, B-tile pinned per XCD)
    int mt = blockIdx.y;   // 0..14
    int tid  = threadIdx.x;
    int wave = tid >> 6, lane = tid & 63;
    int wm = wave >> 1;
    int wn = wave & 1;
    int lr = lane & 15;
    int lk = lane >> 4;

    int rs = tid >> 3;
    int cs = tid & 7;
    const short* Ag = (const short*)hA  + ((size_t)mt * 256 + rs) * HH + cs * 8;
    const short* Bg = (const short*)wfc + ((size_t)nt * 128 + rs) * HH + cs * 8;
    int wofsA[4], wofsB[2];
#pragma unroll
    for (int s = 0; s < 4; ++s) {
        int row = s * 64 + rs;
        wofsA[s] = row * 128 + ((cs ^ (row & 7)) * 16);
    }
#pragma unroll
    for (int s = 0; s < 2; ++s) {
        int row = s * 64 + rs;
        wofsB[s] = row * 128 + ((cs ^ (row & 7)) * 16);
    }

    f32x4 acc[4][4] = {};

#define LOADT(kt, GA, GB)                                                        \
    do {                                                                         \
        _Pragma("unroll") for (int s = 0; s < 4; ++s)                            \
            GA[s] = *(const bf16x8*)(Ag + (size_t)s * 64 * HH + (kt) * 64);      \
        _Pragma("unroll") for (int s = 0; s < 2; ++s)                            \
            GB[s] = *(const bf16x8*)(Bg + (size_t)s * 64 * HH + (kt) * 64);      \
    } while (0)

#define STORET(GA, GB)                                                           \
    do {                                                                         \
        _Pragma("unroll") for (int s = 0; s < 4; ++s)                            \
            *(bf16x8*)(AsB + wofsA[s]) = GA[s];                                  \
        _Pragma("unroll") for (int s = 0; s < 2; ++s)                            \
            *(bf16x8*)(BsB + wofsB[s]) = GB[s];                                  \
    } while (0)

#define COMPUTE()                                                                \
    do {                                                                         \
        _Pragma("unroll") for (int kk = 0; kk < 2; ++kk) {                       \
            bf16x8 af[4], bg[4];                                                 \
            _Pragma("unroll") for (int i = 0; i < 4; ++i) {                      \
                int r = wm * 64 + i * 16 + lr;                                   \
                af[i] = *(const bf16x8*)(AsB + r * 128 + (((kk * 4 + lk) ^ (r & 7)) * 16)); \
            }                                                                    \
            _Pragma("unroll") for (int j = 0; j < 4; ++j) {                      \
                int r = wn * 64 + j * 16 + lr;                                   \
                bg[j] = *(const bf16x8*)(BsB + r * 128 + (((kk * 4 + lk) ^ (r & 7)) * 16)); \
            }                                                                    \
            _Pragma("unroll") for (int i = 0; i < 4; ++i)                        \
                _Pragma("unroll") for (int j = 0; j < 4; ++j)                    \
                    acc[i][j] = __builtin_amdgcn_mfma_f32_16x16x32_bf16(af[i], bg[j], acc[i][j], 0, 0, 0); \
        }                                                                        \
    } while (0)

    bf16x8 gA[4], gB[2], gA2[4], gB2[2];
    LOADT(0, gA, gB);
    STORET(gA, gB);   LOADT(1, gA2, gB2); __syncthreads(); COMPUTE(); __syncthreads();
    STORET(gA2, gB2); LOADT(2, gA, gB);   __syncthreads(); COMPUTE(); __syncthreads();
    STORET(gA, gB);   LOADT(3, gA2, gB2); __syncthreads(); COMPUTE(); __syncthreads();
    STORET(gA2, gB2);                     __syncthreads(); COMPUTE();

#undef LOADT
#undef STORET
#undef COMPUTE

    int m_base = mt * 256 + wm * 64;
    int n_base = nt * 128 + wn * 64;
#pragma unroll
    for (int i = 0; i < 4; ++i) {
#pragma unroll
        for (int j = 0; j < 4; ++j) {
            int v = n_base + j * 16 + lr;
            float bias = b_fc[v];
#pragma unroll
            for (int q = 0; q < 4; ++q) {
                int m = m_base + i * 16 + lk * 4 + q;
                out[(size_t)m * VV + v] = acc[i][j][q] + bias;
            }
        }
    }
}

extern "C" void kernel_launch(void* const* d_in, const int* in_sizes, int n_in,
                              void* d_out, int out_size, void* d_ws, size_t ws_size,
                              hipStream_t stream) {
    (void)in_sizes; (void)n_in; (void)out_size;
    const float* features   = (const float*)d_in[0];
    const float* embeddings = (const float*)d_in[1];
    const float* W_init     = (const float*)d_in[2];
    const float* b_init     = (const float*)d_in[3];
    const float* W_fc2      = (const float*)d_in[4];
    const float* b_fc2      = (const float*)d_in[5];
    const float* W_ih       = (const float*)d_in[6];
    const float* b_ih       = (const float*)d_in[7];
    const float* W_hh       = (const float*)d_in[8];
    const float* b_hh       = (const float*)d_in[9];
    const float* W_fc       = (const float*)d_in[10];
    const float* b_fc       = (const float*)d_in[11];

    char* ws = (char*)d_ws;
    float* feat   = (float*)(ws + 65536);                      // 32 KB
    float* hbuf0  = (float*)(ws + 98304);                      // 32 KB
    __hip_bfloat16* hA = (__hip_bfloat16*)(ws + 131072);       // 1.875 MB (ends 2,097,152)
    float* gi     = (float*)(ws + 2097152);                    // 11.25 MB (ends 13,893,632)
    unsigned int* whh_bf = (unsigned int*)(ws + 13893632);     // 393 KB (ends 14,286,848)
    float* outp = (float*)d_out;
    // part (8 MB) lives in d_out's tail: consumed by fc2b, fully overwritten by k_logits later
    float* part = (float*)d_out + 120782848;                   // 122,880,000 - 2,097,152

    // disjoint-wfc layout needs 14,286,848 + 16,384,000 = 30,670,848 bytes
    int fused = (ws_size >= 30670848u);
    __hip_bfloat16* wfc = fused ? (__hip_bfloat16*)(ws + 14286848)   // disjoint from gi
                                : (__hip_bfloat16*)(ws + 2097152);   // overlays gi (after gru)

    k_pre<<<1616, 256, 0, stream>>>(features, W_fc2, part, W_hh, whh_bf, W_init, b_init,
                                    hbuf0, embeddings, W_ih, gi);
    k_fc2b<<<dim3(32, 8), 256, 0, stream>>>(part, b_fc2, feat);
    if (fused) {
        k_gru_cvt<<<32 + 667, 768, 0, stream>>>(hbuf0, gi, whh_bf, b_hh, feat, W_ih, b_ih,
                                                hA, W_fc, wfc);
    } else {
        k_gru<<<32, 768, 0, stream>>>(hbuf0, gi, whh_bf, b_hh, feat, W_ih, b_ih, hA);
        k_cvt<<<8000, 256, 0, stream>>>(W_fc, wfc);
    }
    k_logits<<<dim3(250, 15), 512, 0, stream>>>(hA, wfc, b_fc, outp);
}